// Round 8
// baseline (201.349 us; speedup 1.0000x reference)
//
#include <hip/hip_runtime.h>
#include <math.h>

#define N_F   128
#define N_D   2048
#define BATCH 8
#define ALPHA 0.2f
#define NC    4      // d-chunks per firefly (512 floats each)

// ws layout (floats):
//   [0   .. 127]   sq_orig[i]
//   [128 .. 255]   sq_final[i]  (zeroed by K1, atomic-accumulated by K23)
//   [512 ..]       pos_final rows (128 x 2048)
#define WS_SQO   0
#define WS_SQF   128
#define WS_POSF  512

// K1: per-firefly squared norm of original positions; zero sq_final slot.
__global__ __launch_bounds__(256) void ff_k1_norms(const float* __restrict__ pos,
                                                   float* __restrict__ ws) {
    const int i   = blockIdx.x;
    const int tid = threadIdx.x;            // 256 threads
    const float* row = pos + (size_t)i * N_D;
    float4 a = *(const float4*)(row + tid * 4);
    float4 b = *(const float4*)(row + 1024 + tid * 4);
    float ss = a.x*a.x + a.y*a.y + a.z*a.z + a.w*a.w
             + b.x*b.x + b.y*b.y + b.z*b.z + b.w*b.w;
    __shared__ float red[256];
    red[tid] = ss;
    __syncthreads();
    for (int s = 128; s > 0; s >>= 1) {
        if (tid < s) red[tid] += red[tid + s];
        __syncthreads();
    }
    if (tid == 0) {
        ws[WS_SQO + i] = red[0];
        ws[WS_SQF + i] = 0.0f;   // init for K23's atomic accumulation
    }
}

// K23: accept + accumulate + fold + norm partial.
// Grid (128 i, 4 c) = 512 blocks x 128 threads: each block owns a 512-float
// d-chunk, so the rank-127 straggler reads 254 KB (was 508 KB) and 2
// blocks/CU + dynamic packing balances per-CU bytes. Association per (i,d)
// unchanged: full accepted list, per-16-j slice sums, one in-order
// accumulator. Norm joined by 4-way commutative atomicAdd (distinct addr/i).
__global__ __launch_bounds__(128) void ff_k23(const float* __restrict__ noise,
                                              const float* __restrict__ pos,
                                              float* __restrict__ ws) {
    const int i    = blockIdx.x;
    const int c    = blockIdx.y;
    const int tid  = threadIdx.x;           // 128 threads (2 waves)
    const int wave = tid >> 6;
    const int lane = tid & 63;

    __shared__ float s_sq[N_F];
    __shared__ unsigned char s_list[N_F];
    __shared__ int s_off[9];
    __shared__ unsigned long long s_m[2];
    __shared__ float red[128];

    s_sq[tid] = ws[WS_SQO + tid];           // 128 threads load 128 norms
    __syncthreads();
    const float si = s_sq[i];

    {
        const int j = wave * 64 + lane;
        const bool cond = (j != i) && (s_sq[j] < si);
        const unsigned long long m = __ballot(cond);
        if (lane == 0) s_m[wave] = m;
    }
    __syncthreads();
    if (tid == 0) {
        int off = 0;
        #pragma unroll
        for (int jc = 0; jc < 8; ++jc) {
            s_off[jc] = off;
            const unsigned long long m = s_m[jc >> 2];
            off += __popcll((m >> ((jc & 3) * 16)) & 0xFFFFULL);
        }
        s_off[8] = off;
    }
    __syncthreads();
    {
        const int j = wave * 64 + lane;
        const bool cond = (j != i) && (s_sq[j] < si);
        if (cond) {
            const unsigned long long m = s_m[wave];
            const int base = s_off[wave * 4];
            const int p    = __popcll(m & ((1ULL << lane) - 1ULL));
            s_list[base + p] = (unsigned char)j;
        }
    }
    __syncthreads();

    const int d0 = c * 512 + tid * 4;       // 512-float chunk per block
    const float* nbase = noise + (size_t)i * (N_F * N_D) + d0;
    const float4 p = *(const float4*)(pos + (size_t)i * N_D + d0);

    float4 acc = make_float4(0.f, 0.f, 0.f, 0.f);
    #pragma unroll 1
    for (int jc = 0; jc < 8; ++jc) {
        const int beg = s_off[jc];
        const int end = s_off[jc + 1];
        float4 s = make_float4(0.f, 0.f, 0.f, 0.f);
        int t = beg;
        for (; t + 16 <= end; t += 16) {
            const float4 v0  = *(const float4*)(nbase + ((size_t)s_list[t]      << 11));
            const float4 v1  = *(const float4*)(nbase + ((size_t)s_list[t + 1]  << 11));
            const float4 v2  = *(const float4*)(nbase + ((size_t)s_list[t + 2]  << 11));
            const float4 v3  = *(const float4*)(nbase + ((size_t)s_list[t + 3]  << 11));
            const float4 v4  = *(const float4*)(nbase + ((size_t)s_list[t + 4]  << 11));
            const float4 v5  = *(const float4*)(nbase + ((size_t)s_list[t + 5]  << 11));
            const float4 v6  = *(const float4*)(nbase + ((size_t)s_list[t + 6]  << 11));
            const float4 v7  = *(const float4*)(nbase + ((size_t)s_list[t + 7]  << 11));
            const float4 v8  = *(const float4*)(nbase + ((size_t)s_list[t + 8]  << 11));
            const float4 v9  = *(const float4*)(nbase + ((size_t)s_list[t + 9]  << 11));
            const float4 v10 = *(const float4*)(nbase + ((size_t)s_list[t + 10] << 11));
            const float4 v11 = *(const float4*)(nbase + ((size_t)s_list[t + 11] << 11));
            const float4 v12 = *(const float4*)(nbase + ((size_t)s_list[t + 12] << 11));
            const float4 v13 = *(const float4*)(nbase + ((size_t)s_list[t + 13] << 11));
            const float4 v14 = *(const float4*)(nbase + ((size_t)s_list[t + 14] << 11));
            const float4 v15 = *(const float4*)(nbase + ((size_t)s_list[t + 15] << 11));
            s.x += v0.x;  s.y += v0.y;  s.z += v0.z;  s.w += v0.w;
            s.x += v1.x;  s.y += v1.y;  s.z += v1.z;  s.w += v1.w;
            s.x += v2.x;  s.y += v2.y;  s.z += v2.z;  s.w += v2.w;
            s.x += v3.x;  s.y += v3.y;  s.z += v3.z;  s.w += v3.w;
            s.x += v4.x;  s.y += v4.y;  s.z += v4.z;  s.w += v4.w;
            s.x += v5.x;  s.y += v5.y;  s.z += v5.z;  s.w += v5.w;
            s.x += v6.x;  s.y += v6.y;  s.z += v6.z;  s.w += v6.w;
            s.x += v7.x;  s.y += v7.y;  s.z += v7.z;  s.w += v7.w;
            s.x += v8.x;  s.y += v8.y;  s.z += v8.z;  s.w += v8.w;
            s.x += v9.x;  s.y += v9.y;  s.z += v9.z;  s.w += v9.w;
            s.x += v10.x; s.y += v10.y; s.z += v10.z; s.w += v10.w;
            s.x += v11.x; s.y += v11.y; s.z += v11.z; s.w += v11.w;
            s.x += v12.x; s.y += v12.y; s.z += v12.z; s.w += v12.w;
            s.x += v13.x; s.y += v13.y; s.z += v13.z; s.w += v13.w;
            s.x += v14.x; s.y += v14.y; s.z += v14.z; s.w += v14.w;
            s.x += v15.x; s.y += v15.y; s.z += v15.z; s.w += v15.w;
        }
        for (; t + 8 <= end; t += 8) {
            const float4 v0 = *(const float4*)(nbase + ((size_t)s_list[t]     << 11));
            const float4 v1 = *(const float4*)(nbase + ((size_t)s_list[t + 1] << 11));
            const float4 v2 = *(const float4*)(nbase + ((size_t)s_list[t + 2] << 11));
            const float4 v3 = *(const float4*)(nbase + ((size_t)s_list[t + 3] << 11));
            const float4 v4 = *(const float4*)(nbase + ((size_t)s_list[t + 4] << 11));
            const float4 v5 = *(const float4*)(nbase + ((size_t)s_list[t + 5] << 11));
            const float4 v6 = *(const float4*)(nbase + ((size_t)s_list[t + 6] << 11));
            const float4 v7 = *(const float4*)(nbase + ((size_t)s_list[t + 7] << 11));
            s.x += v0.x; s.y += v0.y; s.z += v0.z; s.w += v0.w;
            s.x += v1.x; s.y += v1.y; s.z += v1.z; s.w += v1.w;
            s.x += v2.x; s.y += v2.y; s.z += v2.z; s.w += v2.w;
            s.x += v3.x; s.y += v3.y; s.z += v3.z; s.w += v3.w;
            s.x += v4.x; s.y += v4.y; s.z += v4.z; s.w += v4.w;
            s.x += v5.x; s.y += v5.y; s.z += v5.z; s.w += v5.w;
            s.x += v6.x; s.y += v6.y; s.z += v6.z; s.w += v6.w;
            s.x += v7.x; s.y += v7.y; s.z += v7.z; s.w += v7.w;
        }
        for (; t + 4 <= end; t += 4) {
            const float4 v0 = *(const float4*)(nbase + ((size_t)s_list[t]     << 11));
            const float4 v1 = *(const float4*)(nbase + ((size_t)s_list[t + 1] << 11));
            const float4 v2 = *(const float4*)(nbase + ((size_t)s_list[t + 2] << 11));
            const float4 v3 = *(const float4*)(nbase + ((size_t)s_list[t + 3] << 11));
            s.x += v0.x; s.y += v0.y; s.z += v0.z; s.w += v0.w;
            s.x += v1.x; s.y += v1.y; s.z += v1.z; s.w += v1.w;
            s.x += v2.x; s.y += v2.y; s.z += v2.z; s.w += v2.w;
            s.x += v3.x; s.y += v3.y; s.z += v3.z; s.w += v3.w;
        }
        for (; t < end; ++t) {
            const float4 v = *(const float4*)(nbase + ((size_t)s_list[t] << 11));
            s.x += v.x; s.y += v.y; s.z += v.z; s.w += v.w;
        }
        acc.x += s.x; acc.y += s.y; acc.z += s.z; acc.w += s.w;
    }

    float4 pf;
    pf.x = fmaf(ALPHA, acc.x, p.x);
    pf.y = fmaf(ALPHA, acc.y, p.y);
    pf.z = fmaf(ALPHA, acc.z, p.z);
    pf.w = fmaf(ALPHA, acc.w, p.w);
    *(float4*)(ws + WS_POSF + (size_t)i * N_D + d0) = pf;

    float ss2 = pf.x*pf.x + pf.y*pf.y + pf.z*pf.z + pf.w*pf.w;
    red[tid] = ss2;
    __syncthreads();
    for (int s = 64; s > 0; s >>= 1) {
        if (tid < s) red[tid] += red[tid + s];
        __syncthreads();
    }
    if (tid == 0) atomicAdd(&ws[WS_SQF + i], red[0]);  // 4-way, distinct addrs
}

// K4: argmin over sq_final (first-index tie-break) + broadcast to (BATCH, N_D).
__global__ __launch_bounds__(256) void ff_k4_out(const float* __restrict__ best_intensity,
                                                 const float* __restrict__ best_position,
                                                 const float* __restrict__ ws,
                                                 float* __restrict__ out) {
    const int tid = threadIdx.x;            // 256 threads, 16 blocks
    __shared__ float sv[N_F];
    __shared__ int   sidx[N_F];
    if (tid < N_F) { sv[tid] = ws[WS_SQF + tid]; sidx[tid] = tid; }
    __syncthreads();
    for (int s = 64; s > 0; s >>= 1) {
        if (tid < s) {
            float v2 = sv[tid + s];
            int   i2 = sidx[tid + s];
            if (v2 < sv[tid] || (v2 == sv[tid] && i2 < sidx[tid])) {
                sv[tid] = v2; sidx[tid] = i2;
            }
        }
        __syncthreads();
    }
    const int  best   = sidx[0];
    const bool better = sqrtf(sv[0]) < best_intensity[0];
    const float* src  = better ? (ws + WS_POSF + (size_t)best * N_D)
                               : best_position;
    const int t = blockIdx.x * 256 + tid;   // 0..4095 float4 slots
    const int d = (t << 2) & (N_D - 1);
    float4 v = *(const float4*)(src + d);
    *(float4*)(out + (size_t)t * 4) = v;
}

extern "C" void kernel_launch(void* const* d_in, const int* in_sizes, int n_in,
                              void* d_out, int out_size, void* d_ws, size_t ws_size,
                              hipStream_t stream) {
    const float* positions      = (const float*)d_in[1];
    const float* noise          = (const float*)d_in[2];
    const float* best_position  = (const float*)d_in[3];
    const float* best_intensity = (const float*)d_in[4];
    float* ws  = (float*)d_ws;
    float* out = (float*)d_out;

    ff_k1_norms<<<N_F, 256, 0, stream>>>(positions, ws);
    dim3 g23(N_F, NC);
    ff_k23<<<g23, 128, 0, stream>>>(noise, positions, ws);
    ff_k4_out<<<16, 256, 0, stream>>>(best_intensity, best_position, ws, out);
}